// Round 2
// baseline (734.279 us; speedup 1.0000x reference)
//
#include <hip/hip_runtime.h>
#include <hip/hip_bf16.h>

// Problem constants
#define B_   4
#define NQ_  2048
#define NK_  2048
#define D_   1024
#define H_   16
#define DH_  64
#define SCALE_ 0.125f

typedef __attribute__((ext_vector_type(8))) __bf16 bf16x8;
typedef __attribute__((ext_vector_type(4))) float  f32x4;

typedef const __attribute__((address_space(1))) unsigned int* gas1p;
typedef __attribute__((address_space(3))) unsigned int*       las3p;

__device__ __forceinline__ f32x4 mfma16(bf16x8 a, bf16x8 b, f32x4 c) {
  return __builtin_amdgcn_mfma_f32_16x16x32_bf16(a, b, c, 0, 0, 0);
}
__device__ __forceinline__ void gload_lds16(const void* g, void* l) {
  __builtin_amdgcn_global_load_lds((gas1p)g, (las3p)l, 16, 0, 0);
}
__device__ __forceinline__ float nn_(float x) {
  if (__builtin_isnan(x)) return 0.0f;
  if (__builtin_isinf(x)) return x > 0.f ? 3.402823466e38f : -3.402823466e38f;
  return x;
}
__device__ __forceinline__ float exp2_(float x) {
#if __has_builtin(__builtin_amdgcn_exp2f)
  return __builtin_amdgcn_exp2f(x);
#else
  return __expf(x * 0.69314718056f);
#endif
}

// ---------------- fp32 -> bf16 convert (vectorized) ----------------
__global__ __launch_bounds__(256) void cvt_bf16_k(const float* __restrict__ s,
                                                  __bf16* __restrict__ d, int n) {
  int i = (blockIdx.x * blockDim.x + threadIdx.x) << 2;
  if (i >= n) return;
  float4 v = *(const float4*)(s + i);
  __bf16 o[4] __attribute__((aligned(8))) = {(__bf16)v.x, (__bf16)v.y, (__bf16)v.z, (__bf16)v.w};
  *(uint2*)(d + i) = *(uint2*)o;
}

// ------------- weight transpose + convert: src[K][N] -> dst[N][K] -------------
__global__ __launch_bounds__(256) void transpose_cvt_k(const float* __restrict__ src,
                                                       __bf16* __restrict__ dst,
                                                       int K, int N) {
  __shared__ float t[32][33];
  int n0 = blockIdx.x * 32, k0 = blockIdx.y * 32;
  int x = threadIdx.x, y0 = threadIdx.y;
  for (int yy = y0; yy < 32; yy += 8)
    t[yy][x] = src[(size_t)(k0 + yy) * N + n0 + x];
  __syncthreads();
  for (int yy = y0; yy < 32; yy += 8)
    dst[(size_t)(n0 + yy) * K + k0 + x] = (__bf16)t[x][yy];
}

// ---------------- m97-structure GEMM: C[M][N] = A[M][K] @ Bt[N][K]^T + bias ----------------
// 128x128 tile, BK=32, 4 waves (2x2), 4x4 16x16x32 fragments per wave.
template <bool OUT_BF16, bool RES>
__global__ __launch_bounds__(256) void gemm_bt_k(const __bf16* __restrict__ A,
                                                 const __bf16* __restrict__ Bt,
                                                 const float* __restrict__ bias,
                                                 const float* __restrict__ res,
                                                 void* __restrict__ out,
                                                 int M, int N, int K) {
  __shared__ __attribute__((aligned(16))) __bf16 As[128 * 32];
  __shared__ __attribute__((aligned(16))) __bf16 Bs[128 * 32];
  const int tid = threadIdx.x, lane = tid & 63, wid = tid >> 6;
  const int wr = wid >> 1, wc = wid & 1;
  const int g = lane >> 4, lr = lane & 15;
  const int m0 = blockIdx.y * 128, n0 = blockIdx.x * 128;

  const f32x4 zero4 = {0.f, 0.f, 0.f, 0.f};
  f32x4 acc[4][4];
#pragma unroll
  for (int m = 0; m < 4; m++)
#pragma unroll
    for (int n = 0; n < 4; n++) acc[m][n] = zero4;

  for (int k0 = 0; k0 < K; k0 += 32) {
    __syncthreads();  // previous iteration's LDS reads complete
#pragma unroll
    for (int i = 0; i < 2; i++) {
      int c = wid * 128 + i * 64 + lane;  // 16B chunk id in [0,512)
      gload_lds16(A + (size_t)(m0 + (c >> 2)) * K + k0 + ((c & 3) << 3),
                  (char*)As + wid * 2048 + i * 1024);
      gload_lds16(Bt + (size_t)(n0 + (c >> 2)) * K + k0 + ((c & 3) << 3),
                  (char*)Bs + wid * 2048 + i * 1024);
    }
    __syncthreads();  // staging drained (compiler emits vmcnt(0))

    bf16x8 af[4], bfv[4];
#pragma unroll
    for (int m = 0; m < 4; m++)
      af[m] = *(const bf16x8*)(As + (wr * 64 + m * 16 + lr) * 32 + g * 8);
#pragma unroll
    for (int n = 0; n < 4; n++)
      bfv[n] = *(const bf16x8*)(Bs + (wc * 64 + n * 16 + lr) * 32 + g * 8);
#pragma unroll
    for (int m = 0; m < 4; m++)
#pragma unroll
      for (int n = 0; n < 4; n++) acc[m][n] = mfma16(af[m], bfv[n], acc[m][n]);
  }

  // epilogue: C row = m0+wr*64+m*16+(lane>>4)*4+r ; col = n0+wc*64+n*16+(lane&15)
#pragma unroll
  for (int m = 0; m < 4; m++) {
    int row = m0 + wr * 64 + m * 16 + g * 4;
#pragma unroll
    for (int n = 0; n < 4; n++) {
      int col = n0 + wc * 64 + n * 16 + lr;
      float bv = bias[col];
#pragma unroll
      for (int r = 0; r < 4; r++) {
        size_t idx = (size_t)(row + r) * N + col;
        float v = acc[m][n][r] + bv;
        if (RES) v = nn_(v + res[idx]);
        if (OUT_BF16) ((__bf16*)out)[idx] = (__bf16)v;
        else          ((float*)out)[idx] = v;
      }
    }
  }
}

// ------------- per-head V transpose: KV_bf[B*NK][2048] -> Vt[(b*H+h)*64+d][NK] -------------
__global__ __launch_bounds__(256) void reorder_v_k(const __bf16* __restrict__ kv,
                                                   __bf16* __restrict__ vt) {
  __shared__ __attribute__((aligned(16))) __bf16 t[64][72];  // 144B stride (16B-aligned rows)
  int bh = blockIdx.y, b = bh >> 4, h = bh & 15;
  int kk0 = blockIdx.x * 64;
  int tid = threadIdx.x;
#pragma unroll
  for (int i = 0; i < 2; i++) {
    int c = tid + i * 256;          // 512 chunks of 8 bf16
    int kk = c >> 3, dc = c & 7;
    const __bf16* src = kv + (size_t)(b * NK_ + kk0 + kk) * 2048 + 1024 + h * 64 + dc * 8;
    *(float4*)&t[kk][dc * 8] = *(const float4*)src;
  }
  __syncthreads();
#pragma unroll
  for (int i = 0; i < 2; i++) {
    int c = tid + i * 256;
    int d = c >> 3, gch = c & 7;
    __bf16 tmp[8] __attribute__((aligned(16)));
#pragma unroll
    for (int j = 0; j < 8; j++) tmp[j] = t[gch * 8 + j][d];
    __bf16* dst = vt + ((size_t)bh * 64 + d) * (size_t)NK_ + kk0 + gch * 8;
    *(float4*)dst = *(float4*)tmp;
  }
}

// ---------------- flash attention (no K/V staging, swapped QK^T) ----------------
// grid: (NQ/64, B*H), 256 threads = 4 independent waves x 16 q-rows. KVBLK=64.
// No __syncthreads anywhere: K read direct from KV_bf, V direct from Vt (L1/L2-resident).
// Swapped S = mfma(K, Q): lane (g,lr) holds S[q=lr][k=n*16+g*4+r] -> softmax row is
// in-lane 16-reduce + 2 shfl_xor. P round-trips through a per-wave 2KB LDS buffer:
// 4x ds_write_b64 (quads, XOR-swizzled to 2-way banking) + 2x ds_read_b128.
__global__ __launch_bounds__(256) void attn_k(const __bf16* __restrict__ Qg,
                                              const __bf16* __restrict__ KVg,
                                              const __bf16* __restrict__ Vt,
                                              __bf16* __restrict__ AO) {
  __shared__ __attribute__((aligned(16))) __bf16 Pl[4][16 * 64];  // 8KB
  const int tid = threadIdx.x, lane = tid & 63, wid = tid >> 6;
  const int g = lane >> 4, lr = lane & 15;
  const int bh = blockIdx.y, b = bh >> 4, h = bh & 15;
  const int qbase = blockIdx.x * 64 + wid * 16;
  const float C2 = SCALE_ * 1.44269504089f;  // fold softmax scale into log2 domain

  // Q fragments (B-operand): col q = lr, k-dim d = ds*32 + g*8 .. +8
  bf16x8 qf[2];
  {
    const __bf16* qp = Qg + ((size_t)(b * NQ_ + qbase + lr)) * 1024 + h * 64 + g * 8;
    qf[0] = *(const bf16x8*)qp;
    qf[1] = *(const bf16x8*)(qp + 32);
  }

  const f32x4 zero4 = {0.f, 0.f, 0.f, 0.f};
  f32x4 po[4];
#pragma unroll
  for (int df = 0; df < 4; df++) po[df] = zero4;
  float m2 = -1e30f, l = 0.f;

  char* pw = (char*)&Pl[wid][0];
  const int swz = (lr & 7) << 4;
  int wa[4], ra[2];
#pragma unroll
  for (int n = 0; n < 4; n++) wa[n] = lr * 128 + ((n * 32 + g * 8) ^ swz);
#pragma unroll
  for (int ks = 0; ks < 2; ks++) ra[ks] = lr * 128 + ((ks * 64 + g * 16) ^ swz);

  const __bf16* Kbase = KVg + (size_t)b * NK_ * 2048 + h * 64 + g * 8;
  const __bf16* Vbase = Vt + (size_t)bh * 64 * NK_ + g * 8;

  for (int kv0 = 0; kv0 < NK_; kv0 += 64) {
    // S^T tile: mfma(K, Q) -> lane holds S[q=lr][k=n*16+g*4+r]
    f32x4 sa[4];
    __builtin_amdgcn_s_setprio(1);
#pragma unroll
    for (int n = 0; n < 4; n++) {
      sa[n] = zero4;
#pragma unroll
      for (int ds = 0; ds < 2; ds++) {
        bf16x8 kf = *(const bf16x8*)(Kbase + (size_t)(kv0 + n * 16 + lr) * 2048 + ds * 32);
        sa[n] = mfma16(kf, qf[ds], sa[n]);
      }
    }
    __builtin_amdgcn_s_setprio(0);

    // row max (log2 domain), in-lane then cross-g
    float mx = -1e30f;
#pragma unroll
    for (int n = 0; n < 4; n++)
#pragma unroll
      for (int r = 0; r < 4; r++) {
        float v = sa[n][r] * C2;
        sa[n][r] = v;
        mx = fmaxf(mx, v);
      }
    mx = fmaxf(mx, __shfl_xor(mx, 16));
    mx = fmaxf(mx, __shfl_xor(mx, 32));

    // defer-max (T13): only rescale when max grew by > 11 (P bounded by 2^11)
    if (__any(mx > m2 + 11.0f)) {
      float mn = fmaxf(m2, mx);
      float alpha = exp2_(m2 - mn);
      m2 = mn;
      l *= alpha;
#pragma unroll
      for (int r = 0; r < 4; r++) {
        float ar = __shfl(alpha, g * 4 + r);  // alpha of row q=g*4+r (bpermute)
#pragma unroll
        for (int df = 0; df < 4; df++) po[df][r] *= ar;
      }
    }

    // P = exp2(t - m2), packed quad writes (k = n*16+g*4 .. +3)
    float rs = 0.f;
#pragma unroll
    for (int n = 0; n < 4; n++) {
      union { __bf16 h[4]; uint2 u; } qd;
#pragma unroll
      for (int r = 0; r < 4; r++) {
        float p = exp2_(sa[n][r] - m2);
        rs += p;
        qd.h[r] = (__bf16)p;
      }
      *(uint2*)(pw + wa[n]) = qd.u;  // ds_write_b64
    }
    rs += __shfl_xor(rs, 16);
    rs += __shfl_xor(rs, 32);
    l += rs;

    // read back as A-fragments: P[q=lr][k=ks*32+g*8 .. +8]
    bf16x8 pa[2];
#pragma unroll
    for (int ks = 0; ks < 2; ks++) pa[ks] = *(const bf16x8*)(pw + ra[ks]);

    // PV: O[q][d] += P @ V
    __builtin_amdgcn_s_setprio(1);
#pragma unroll
    for (int df = 0; df < 4; df++) {
#pragma unroll
      for (int ks = 0; ks < 2; ks++) {
        bf16x8 vf = *(const bf16x8*)(Vbase + (size_t)(df * 16 + lr) * NK_ + kv0 + ks * 32);
        po[df] = mfma16(pa[ks], vf, po[df]);
      }
    }
    __builtin_amdgcn_s_setprio(0);
  }

  // epilogue: O / l ; po row q = g*4+r, col d = df*16+lr
  float inv = 1.0f / l;
#pragma unroll
  for (int r = 0; r < 4; r++) {
    float ir = __shfl(inv, g * 4 + r);
    size_t row = (size_t)(b * NQ_ + qbase + g * 4 + r);
#pragma unroll
    for (int df = 0; df < 4; df++)
      AO[row * 1024 + h * 64 + df * 16 + lr] = (__bf16)(po[df][r] * ir);
  }
}

extern "C" void kernel_launch(void* const* d_in, const int* in_sizes, int n_in,
                              void* d_out, int out_size, void* d_ws, size_t ws_size,
                              hipStream_t stream) {
  (void)in_sizes; (void)n_in; (void)out_size; (void)ws_size;
  const float* x_q  = (const float*)d_in[0];
  const float* x_kv = (const float*)d_in[1];
  const float* Wq   = (const float*)d_in[2];
  const float* bq   = (const float*)d_in[3];
  const float* Wkv  = (const float*)d_in[4];
  const float* bkv  = (const float*)d_in[5];
  const float* Wp   = (const float*)d_in[6];
  const float* bp   = (const float*)d_in[7];

  char* w = (char*)d_ws;
  __bf16* xq_bf  = (__bf16*)w; w += (size_t)8388608 * 2;   // [8192][1024]
  __bf16* xkv_bf = (__bf16*)w; w += (size_t)8388608 * 2;   // [8192][1024]
  __bf16* Wq_t   = (__bf16*)w; w += (size_t)1048576 * 2;   // [1024][1024]
  __bf16* Wkv_t  = (__bf16*)w; w += (size_t)2097152 * 2;   // [2048][1024]
  __bf16* Wp_t   = (__bf16*)w; w += (size_t)1048576 * 2;   // [1024][1024]
  __bf16* Q_bf   = (__bf16*)w; w += (size_t)8388608 * 2;   // [8192][1024]
  __bf16* KV_bf  = (__bf16*)w; w += (size_t)16777216 * 2;  // [8192][2048]
  __bf16* Vt     = (__bf16*)w; w += (size_t)8388608 * 2;   // [64*64][2048]
  __bf16* AO     = (__bf16*)w; w += (size_t)8388608 * 2;   // [8192][1024]

  cvt_bf16_k<<<8192, 256, 0, stream>>>(x_q, xq_bf, 8388608);
  cvt_bf16_k<<<8192, 256, 0, stream>>>(x_kv, xkv_bf, 8388608);
  transpose_cvt_k<<<dim3(32, 32), dim3(32, 8), 0, stream>>>(Wq, Wq_t, 1024, 1024);
  transpose_cvt_k<<<dim3(64, 32), dim3(32, 8), 0, stream>>>(Wkv, Wkv_t, 1024, 2048);
  transpose_cvt_k<<<dim3(32, 32), dim3(32, 8), 0, stream>>>(Wp, Wp_t, 1024, 1024);

  gemm_bt_k<true, false><<<dim3(8, 64), 256, 0, stream>>>(xq_bf, Wq_t, bq, nullptr, Q_bf, 8192, 1024, 1024);
  gemm_bt_k<true, false><<<dim3(16, 64), 256, 0, stream>>>(xkv_bf, Wkv_t, bkv, nullptr, KV_bf, 8192, 2048, 1024);
  reorder_v_k<<<dim3(32, 64), 256, 0, stream>>>(KV_bf, Vt);
  attn_k<<<dim3(32, 64), 256, 0, stream>>>(Q_bf, KV_bf, Vt, AO);
  gemm_bt_k<false, true><<<dim3(8, 64), 256, 0, stream>>>(AO, Wp_t, bp, x_q, d_out, 8192, 1024, 1024);
}

// Round 3
// 405.219 us; speedup vs baseline: 1.8121x; 1.8121x over previous
//
#include <hip/hip_runtime.h>
#include <hip/hip_bf16.h>

// Problem constants
#define B_   4
#define NQ_  2048
#define NK_  2048
#define D_   1024
#define H_   16
#define DH_  64
#define SCALE_ 0.125f

typedef __attribute__((ext_vector_type(8))) __bf16 bf16x8;
typedef __attribute__((ext_vector_type(4))) float  f32x4;

typedef const __attribute__((address_space(1))) unsigned int* gas1p;
typedef __attribute__((address_space(3))) unsigned int*       las3p;

__device__ __forceinline__ f32x4 mfma16(bf16x8 a, bf16x8 b, f32x4 c) {
  return __builtin_amdgcn_mfma_f32_16x16x32_bf16(a, b, c, 0, 0, 0);
}
__device__ __forceinline__ void gload_lds16(const void* g, void* l) {
  __builtin_amdgcn_global_load_lds((gas1p)g, (las3p)l, 16, 0, 0);
}
__device__ __forceinline__ float nn_(float x) {
  if (__builtin_isnan(x)) return 0.0f;
  if (__builtin_isinf(x)) return x > 0.f ? 3.402823466e38f : -3.402823466e38f;
  return x;
}
__device__ __forceinline__ float exp2_(float x) {
#if __has_builtin(__builtin_amdgcn_exp2f)
  return __builtin_amdgcn_exp2f(x);
#else
  return __expf(x * 0.69314718056f);
#endif
}

// ---------------- fp32 -> bf16 convert (vectorized) ----------------
__global__ __launch_bounds__(256) void cvt_bf16_k(const float* __restrict__ s,
                                                  __bf16* __restrict__ d, int n) {
  int i = (blockIdx.x * blockDim.x + threadIdx.x) << 2;
  if (i >= n) return;
  float4 v = *(const float4*)(s + i);
  __bf16 o[4] __attribute__((aligned(8))) = {(__bf16)v.x, (__bf16)v.y, (__bf16)v.z, (__bf16)v.w};
  *(uint2*)(d + i) = *(uint2*)o;
}

// ------------- weight transpose + convert: src[K][N] -> dst[N][K] -------------
__global__ __launch_bounds__(256) void transpose_cvt_k(const float* __restrict__ src,
                                                       __bf16* __restrict__ dst,
                                                       int K, int N) {
  __shared__ float t[32][33];
  int n0 = blockIdx.x * 32, k0 = blockIdx.y * 32;
  int x = threadIdx.x, y0 = threadIdx.y;
  for (int yy = y0; yy < 32; yy += 8)
    t[yy][x] = src[(size_t)(k0 + yy) * N + n0 + x];
  __syncthreads();
  for (int yy = y0; yy < 32; yy += 8)
    dst[(size_t)(n0 + yy) * K + k0 + x] = (__bf16)t[x][yy];
}

// ---------------- m97-structure GEMM: C[M][N] = A[M][K] @ Bt[N][K]^T + bias ----------------
template <bool OUT_BF16, bool RES>
__global__ __launch_bounds__(256) void gemm_bt_k(const __bf16* __restrict__ A,
                                                 const __bf16* __restrict__ Bt,
                                                 const float* __restrict__ bias,
                                                 const float* __restrict__ res,
                                                 void* __restrict__ out,
                                                 int M, int N, int K) {
  __shared__ __attribute__((aligned(16))) __bf16 As[128 * 32];
  __shared__ __attribute__((aligned(16))) __bf16 Bs[128 * 32];
  const int tid = threadIdx.x, lane = tid & 63, wid = tid >> 6;
  const int wr = wid >> 1, wc = wid & 1;
  const int g = lane >> 4, lr = lane & 15;
  const int m0 = blockIdx.y * 128, n0 = blockIdx.x * 128;

  const f32x4 zero4 = {0.f, 0.f, 0.f, 0.f};
  f32x4 acc[4][4];
#pragma unroll
  for (int m = 0; m < 4; m++)
#pragma unroll
    for (int n = 0; n < 4; n++) acc[m][n] = zero4;

  for (int k0 = 0; k0 < K; k0 += 32) {
    __syncthreads();  // previous iteration's LDS reads complete
#pragma unroll
    for (int i = 0; i < 2; i++) {
      int c = wid * 128 + i * 64 + lane;  // 16B chunk id in [0,512)
      gload_lds16(A + (size_t)(m0 + (c >> 2)) * K + k0 + ((c & 3) << 3),
                  (char*)As + wid * 2048 + i * 1024);
      gload_lds16(Bt + (size_t)(n0 + (c >> 2)) * K + k0 + ((c & 3) << 3),
                  (char*)Bs + wid * 2048 + i * 1024);
    }
    __syncthreads();  // staging drained

    bf16x8 af[4], bfv[4];
#pragma unroll
    for (int m = 0; m < 4; m++)
      af[m] = *(const bf16x8*)(As + (wr * 64 + m * 16 + lr) * 32 + g * 8);
#pragma unroll
    for (int n = 0; n < 4; n++)
      bfv[n] = *(const bf16x8*)(Bs + (wc * 64 + n * 16 + lr) * 32 + g * 8);
#pragma unroll
    for (int m = 0; m < 4; m++)
#pragma unroll
      for (int n = 0; n < 4; n++) acc[m][n] = mfma16(af[m], bfv[n], acc[m][n]);
  }

#pragma unroll
  for (int m = 0; m < 4; m++) {
    int row = m0 + wr * 64 + m * 16 + g * 4;
#pragma unroll
    for (int n = 0; n < 4; n++) {
      int col = n0 + wc * 64 + n * 16 + lr;
      float bv = bias[col];
#pragma unroll
      for (int r = 0; r < 4; r++) {
        size_t idx = (size_t)(row + r) * N + col;
        float v = acc[m][n][r] + bv;
        if (RES) v = nn_(v + res[idx]);
        if (OUT_BF16) ((__bf16*)out)[idx] = (__bf16)v;
        else          ((float*)out)[idx] = v;
      }
    }
  }
}

// ------------- per-head V transpose: KV_bf[B*NK][2048] -> Vt[(b*H+h)*64+d][NK] -------------
// Vt rows are chunk-swizzled per 128B tile-segment: chunk g holds source kk-chunk g^(d&7),
// so attention can stage linearly with global_load_lds and read swizzled (rule #21).
__global__ __launch_bounds__(256) void reorder_v_k(const __bf16* __restrict__ kv,
                                                   __bf16* __restrict__ vt) {
  __shared__ __attribute__((aligned(16))) __bf16 t[64][72];  // 144B stride (16B-aligned rows)
  int bh = blockIdx.y, b = bh >> 4, h = bh & 15;
  int kk0 = blockIdx.x * 64;
  int tid = threadIdx.x;
#pragma unroll
  for (int i = 0; i < 2; i++) {
    int c = tid + i * 256;          // 512 chunks of 8 bf16
    int kk = c >> 3, dc = c & 7;
    const __bf16* src = kv + (size_t)(b * NK_ + kk0 + kk) * 2048 + 1024 + h * 64 + dc * 8;
    *(float4*)&t[kk][dc * 8] = *(const float4*)src;
  }
  __syncthreads();
#pragma unroll
  for (int i = 0; i < 2; i++) {
    int c = tid + i * 256;
    int d = c >> 3, gch = c & 7;
    int s = gch ^ (d & 7);
    __bf16 tmp[8] __attribute__((aligned(16)));
#pragma unroll
    for (int j = 0; j < 8; j++) tmp[j] = t[s * 8 + j][d];
    __bf16* dst = vt + ((size_t)bh * 64 + d) * (size_t)NK_ + kk0 + gch * 8;
    *(float4*)dst = *(float4*)tmp;
  }
}

// ---------------- flash attention: staged LDS + swapped QK^T + 2-phase pipeline ----------------
// 1D grid 2048 blocks: bh = bid&63 (head->XCD pinning: all q-blocks of head bh on XCD bh%8),
// qblk = bid>>6. 4 waves x 16 q-rows, KVBLK=64, K/V double-buffered in LDS.
// Per tile: STAGE(next buf) -> vmcnt(4) -> s_barrier -> QK^T -> softmax -> P round-trip ->
// PV -> s_barrier. Staging latency hides under current tile's compute; vmcnt never drains to 0
// mid-loop (T4). Kt swizzled byte^=((kk&7)<<4) via pre-swizzled global src; Vl swizzle
// pre-applied in Vt layout; P per-wave swizzled quad writes.
__global__ __launch_bounds__(256) void attn_k(const __bf16* __restrict__ Qg,
                                              const __bf16* __restrict__ KVg,
                                              const __bf16* __restrict__ Vt,
                                              __bf16* __restrict__ AO) {
  __shared__ __attribute__((aligned(16))) __bf16 Kt[2][64 * 64];
  __shared__ __attribute__((aligned(16))) __bf16 Vl[2][64 * 64];
  __shared__ __attribute__((aligned(16))) __bf16 Pl[4][16 * 64];
  const int tid = threadIdx.x, lane = tid & 63, wid = tid >> 6;
  const int g = lane >> 4, lr = lane & 15;
  const int bid = blockIdx.x;
  const int bh = bid & 63, b = bh >> 4, h = bh & 15;
  const int qbase = (bid >> 6) * 64 + wid * 16;
  const float C2 = SCALE_ * 1.44269504089f;  // scale * log2(e)

  // Q fragments (B-operand): col q = lr, depth d = ds*32 + g*8 .. +8
  bf16x8 qf[2];
  {
    const __bf16* qp = Qg + ((size_t)(b * NQ_ + qbase + lr)) * 1024 + h * 64 + g * 8;
    qf[0] = *(const bf16x8*)qp;
    qf[1] = *(const bf16x8*)(qp + 32);
  }

  const f32x4 zero4 = {0.f, 0.f, 0.f, 0.f};
  f32x4 po[4];
#pragma unroll
  for (int df = 0; df < 4; df++) po[df] = zero4;
  float m2 = -1e30f, l = 0.f;

  // P round-trip addresses (per-wave buffer, row q, XOR swizzle on row&7)
  char* pw = (char*)&Pl[wid][0];
  const int swz = (lr & 7) << 4;
  int wa[4], ra[2];
#pragma unroll
  for (int n = 0; n < 4; n++) wa[n] = lr * 128 + ((n * 32 + g * 8) ^ swz);
#pragma unroll
  for (int ks = 0; ks < 2; ks++) ra[ks] = lr * 128 + ((ks * 64 + g * 16) ^ swz);

  // staging source bases (per-lane, pre-swizzled for K)
  const int kkw = wid * 16 + (lane >> 3);  // +i*8
  const int cc = lane & 7;
  const __bf16* Ksrc = KVg + (size_t)b * NK_ * 2048 + h * 64;
  const __bf16* Vsrc = Vt + (size_t)bh * 64 * (size_t)NK_;

#define STAGE_(bi, kv0)                                                              \
  {                                                                                  \
    _Pragma("unroll") for (int i = 0; i < 2; i++) {                                  \
      int kk = kkw + i * 8;                                                          \
      gload_lds16(Ksrc + (size_t)((kv0) + kk) * 2048 + ((cc ^ (kk & 7)) << 3),       \
                  (char*)&Kt[bi][0] + wid * 2048 + i * 1024);                        \
      gload_lds16(Vsrc + (size_t)kk * NK_ + (kv0) + (cc << 3),                       \
                  (char*)&Vl[bi][0] + wid * 2048 + i * 1024);                        \
    }                                                                                \
  }

  int cur = 0;
  STAGE_(0, 0);

  for (int t = 0; t < NK_ / 64; ++t) {
    const int kv0 = t << 6;
    if (t < NK_ / 64 - 1) {
      STAGE_(cur ^ 1, kv0 + 64);
      asm volatile("s_waitcnt vmcnt(4)" ::: "memory");  // current tile's 4 loads done
    } else {
      asm volatile("s_waitcnt vmcnt(0)" ::: "memory");
    }
    asm volatile("s_barrier" ::: "memory");  // all waves' current-tile data in LDS

    const char* Kb = (const char*)&Kt[cur][0];
    const char* Vb = (const char*)&Vl[cur][0];

    // S^T = mfma(K, Q): lane holds S[q=lr][k=n*16+g*4+r] (raw, unscaled)
    f32x4 sa[4];
    __builtin_amdgcn_s_setprio(1);
#pragma unroll
    for (int n = 0; n < 4; n++) {
      sa[n] = zero4;
      int kk = n * 16 + lr;
#pragma unroll
      for (int ds = 0; ds < 2; ds++) {
        bf16x8 kf = *(const bf16x8*)(Kb + kk * 128 + ((ds * 64 + g * 16) ^ ((kk & 7) << 4)));
        sa[n] = mfma16(kf, qf[ds], sa[n]);
      }
    }
    __builtin_amdgcn_s_setprio(0);

    // row max on raw S (order-preserving), scale once
    float mx = -1e30f;
#pragma unroll
    for (int n = 0; n < 4; n++)
#pragma unroll
      for (int r = 0; r < 4; r++) mx = fmaxf(mx, sa[n][r]);
    mx = fmaxf(mx, __shfl_xor(mx, 16));
    mx = fmaxf(mx, __shfl_xor(mx, 32));
    mx *= C2;

    // defer-max (T13): rescale only when max grew by >11 (P bounded by 2^11)
    if (__any(mx > m2 + 11.0f)) {
      float mn = fmaxf(m2, mx);
      float alpha = exp2_(m2 - mn);
      m2 = mn;
      l *= alpha;
#pragma unroll
      for (int r = 0; r < 4; r++) {
        float ar = __shfl(alpha, g * 4 + r);  // alpha of row q=g*4+r
#pragma unroll
        for (int df = 0; df < 4; df++) po[df][r] *= ar;
      }
    }

    // P = exp2(fma(s, C2, -m2)), packed quad writes (k = n*16+g*4 .. +3)
    float rs = 0.f;
#pragma unroll
    for (int n = 0; n < 4; n++) {
      union { __bf16 hh[4]; uint2 u; } qd;
#pragma unroll
      for (int r = 0; r < 4; r++) {
        float p = exp2_(fmaf(sa[n][r], C2, -m2));
        rs += p;
        qd.hh[r] = (__bf16)p;
      }
      *(uint2*)(pw + wa[n]) = qd.u;  // ds_write_b64
    }
    rs += __shfl_xor(rs, 16);
    rs += __shfl_xor(rs, 32);
    l += rs;

    // read back as A-fragments: P[q=lr][k=ks*32+g*8 .. +8]
    bf16x8 pa[2];
#pragma unroll
    for (int ks = 0; ks < 2; ks++) pa[ks] = *(const bf16x8*)(pw + ra[ks]);

    // PV: O[q][d] += P @ V
    __builtin_amdgcn_s_setprio(1);
#pragma unroll
    for (int df = 0; df < 4; df++) {
      int d = df * 16 + lr;
#pragma unroll
      for (int ks = 0; ks < 2; ks++) {
        bf16x8 vf = *(const bf16x8*)(Vb + d * 128 + ((ks * 64 + g * 16) ^ ((d & 7) << 4)));
        po[df] = mfma16(pa[ks], vf, po[df]);
      }
    }
    __builtin_amdgcn_s_setprio(0);

    asm volatile("s_barrier" ::: "memory");  // all reads of buf[cur] done -> safe to overwrite
    cur ^= 1;
  }

  // epilogue: O / l ; po row q = g*4+r, col d = df*16+lr
  float inv = 1.0f / l;
#pragma unroll
  for (int r = 0; r < 4; r++) {
    float ir = __shfl(inv, g * 4 + r);
    size_t row = (size_t)(b * NQ_ + qbase + g * 4 + r);
#pragma unroll
    for (int df = 0; df < 4; df++)
      AO[row * 1024 + h * 64 + df * 16 + lr] = (__bf16)(po[df][r] * ir);
  }
#undef STAGE_
}

extern "C" void kernel_launch(void* const* d_in, const int* in_sizes, int n_in,
                              void* d_out, int out_size, void* d_ws, size_t ws_size,
                              hipStream_t stream) {
  (void)in_sizes; (void)n_in; (void)out_size; (void)ws_size;
  const float* x_q  = (const float*)d_in[0];
  const float* x_kv = (const float*)d_in[1];
  const float* Wq   = (const float*)d_in[2];
  const float* bq   = (const float*)d_in[3];
  const float* Wkv  = (const float*)d_in[4];
  const float* bkv  = (const float*)d_in[5];
  const float* Wp   = (const float*)d_in[6];
  const float* bp   = (const float*)d_in[7];

  char* w = (char*)d_ws;
  __bf16* xq_bf  = (__bf16*)w; w += (size_t)8388608 * 2;   // [8192][1024]
  __bf16* xkv_bf = (__bf16*)w; w += (size_t)8388608 * 2;   // [8192][1024]
  __bf16* Wq_t   = (__bf16*)w; w += (size_t)1048576 * 2;   // [1024][1024]
  __bf16* Wkv_t  = (__bf16*)w; w += (size_t)2097152 * 2;   // [2048][1024]
  __bf16* Wp_t   = (__bf16*)w; w += (size_t)1048576 * 2;   // [1024][1024]
  __bf16* Q_bf   = (__bf16*)w; w += (size_t)8388608 * 2;   // [8192][1024]
  __bf16* KV_bf  = (__bf16*)w; w += (size_t)16777216 * 2;  // [8192][2048]
  __bf16* Vt     = (__bf16*)w; w += (size_t)8388608 * 2;   // [64*64][2048]
  __bf16* AO     = (__bf16*)w; w += (size_t)8388608 * 2;   // [8192][1024]

  cvt_bf16_k<<<8192, 256, 0, stream>>>(x_q, xq_bf, 8388608);
  cvt_bf16_k<<<8192, 256, 0, stream>>>(x_kv, xkv_bf, 8388608);
  transpose_cvt_k<<<dim3(32, 32), dim3(32, 8), 0, stream>>>(Wq, Wq_t, 1024, 1024);
  transpose_cvt_k<<<dim3(64, 32), dim3(32, 8), 0, stream>>>(Wkv, Wkv_t, 1024, 2048);
  transpose_cvt_k<<<dim3(32, 32), dim3(32, 8), 0, stream>>>(Wp, Wp_t, 1024, 1024);

  gemm_bt_k<true, false><<<dim3(8, 64), 256, 0, stream>>>(xq_bf, Wq_t, bq, nullptr, Q_bf, 8192, 1024, 1024);
  gemm_bt_k<true, false><<<dim3(16, 64), 256, 0, stream>>>(xkv_bf, Wkv_t, bkv, nullptr, KV_bf, 8192, 2048, 1024);
  reorder_v_k<<<dim3(32, 64), 256, 0, stream>>>(KV_bf, Vt);
  attn_k<<<2048, 256, 0, stream>>>(Q_bf, KV_bf, Vt, AO);
  gemm_bt_k<false, true><<<dim3(8, 64), 256, 0, stream>>>(AO, Wp_t, bp, x_q, d_out, 8192, 1024, 1024);
}